// Round 4
// baseline (216.129 us; speedup 1.0000x reference)
//
#include <hip/hip_runtime.h>
#include <hip/hip_bf16.h>

#define NROWS 8192
#define SD 512
#define FDIM 128
#define KNN 10
#define C_CONST 1.0e-3f
#define L_CONST 5.0f
#define EPS_CONST 1.0e-3f
#define BIGF 3.0e38f
#define BCAP 17
#define TRIG 12
#define NSEG 16

typedef float f32x4 __attribute__((ext_vector_type(4)));
typedef __bf16 bf16x8 __attribute__((ext_vector_type(8)));
typedef unsigned short ushort4v __attribute__((ext_vector_type(4)));

union U8 { unsigned short u[8]; bf16x8 b; };

__device__ __forceinline__ unsigned short f32_to_bf16_rne(float f) {
    unsigned int x = __float_as_uint(f);
    unsigned int lsb = (x >> 16) & 1u;
    x += 0x7fffu + lsb;
    return (unsigned short)(x >> 16);
}

__device__ __forceinline__ void split_bf16(float v, unsigned short& h, unsigned short& l) {
    unsigned short hh = f32_to_bf16_rne(v);
    float hf = __uint_as_float(((unsigned int)hh) << 16);
    h = hh;
    l = f32_to_bf16_rne(v - hf);
}

__device__ __forceinline__ void insert10(float* vals, float tv) {
    #pragma unroll
    for (int u = 0; u < 10; ++u) {
        float lo = fminf(vals[u], tv);
        tv = fmaxf(vals[u], tv);
        vals[u] = lo;
    }
}

__device__ __forceinline__ void compact16(float* vals, const float* bp, int cnt) {
    #pragma unroll
    for (int i = 0; i < 16; ++i) {
        float tv = (i < cnt) ? bp[i] : BIGF;
        insert10(vals, tv);
    }
}

__device__ __forceinline__ void ce(float& a, float& b) {
    float lo = fminf(a, b), hi = fmaxf(a, b); a = lo; b = hi;
}
__device__ __forceinline__ void sortBitonic10(float* w) {
    ce(w[0],w[8]); ce(w[1],w[9]);
    ce(w[2],w[6]); ce(w[3],w[7]); ce(w[4],w[8]); ce(w[5],w[9]);
    ce(w[2],w[4]); ce(w[3],w[5]); ce(w[6],w[8]); ce(w[7],w[9]);
    ce(w[0],w[1]); ce(w[2],w[3]); ce(w[4],w[5]); ce(w[6],w[7]); ce(w[8],w[9]);
}

// ---------------- K0: weight prep ----------------
__global__ __launch_bounds__(256) void k_prep(
    const float* __restrict__ w1, const float* __restrict__ wt1, const float* __restrict__ wz1,
    const float* __restrict__ w2, const float* __restrict__ wt2, const float* __restrict__ wz2,
    const float* __restrict__ w3, const float* __restrict__ wt3, const float* __restrict__ wz3,
    const float* __restrict__ b1, const float* __restrict__ bt1, const float* __restrict__ bz1,
    const float* __restrict__ b2, const float* __restrict__ bt2, const float* __restrict__ bz2,
    const float* __restrict__ b3, const float* __restrict__ bt3, const float* __restrict__ bz3,
    unsigned short* __restrict__ w1h, unsigned short* __restrict__ w1l,
    unsigned short* __restrict__ w2h, unsigned short* __restrict__ w2l,
    unsigned short* __restrict__ w3h, unsigned short* __restrict__ w3l,
    float* __restrict__ b1c, float* __restrict__ b2c, float* __restrict__ b3c)
{
    const int b = blockIdx.x;
    const int t = threadIdx.x;
    if (b < 192) {
        int idx = (b * 256 + t) * 4;
        int n = idx >> 9, k = idx & 511;
        const float* src = (n < 128) ? (w1 + (size_t)n * 512)
                         : (n < 256) ? (wt1 + (size_t)(n - 128) * 512)
                                     : (wz1 + (size_t)(n - 256) * 512);
        f32x4 v = *(const f32x4*)(src + k);
        ushort4v h, l;
        #pragma unroll
        for (int j = 0; j < 4; ++j) { unsigned short hh, ll; split_bf16(v[j], hh, ll); h[j] = hh; l[j] = ll; }
        *(ushort4v*)(w1h + idx) = h;
        *(ushort4v*)(w1l + idx) = l;
    } else if (b < 264) {
        int idx = ((b - 192) * 256 + t) * 4;
        int n = idx / 384, k = idx % 384;
        f32x4 v = {0.f, 0.f, 0.f, 0.f};
        if (n < 64)       { if (k < 128)             v = *(const f32x4*)(w2  + (size_t)n * 128 + k); }
        else if (n < 128) { if (k >= 128 && k < 256) v = *(const f32x4*)(wt2 + (size_t)(n - 64) * 128 + (k - 128)); }
        else              { if (k >= 256)            v = *(const f32x4*)(wz2 + (size_t)(n - 128) * 128 + (k - 256)); }
        ushort4v h, l;
        #pragma unroll
        for (int j = 0; j < 4; ++j) { unsigned short hh, ll; split_bf16(v[j], hh, ll); h[j] = hh; l[j] = ll; }
        *(ushort4v*)(w2h + idx) = h;
        *(ushort4v*)(w2l + idx) = l;
    } else if (b < 291) {
        int idx = ((b - 264) * 256 + t) * 4;
        int n = idx / 192, k = idx % 192;
        f32x4 v = {0.f, 0.f, 0.f, 0.f};
        if (n == 0)                 { if (k < 64)             v = *(const f32x4*)(w3 + k); }
        else if (n == 1)            { if (k >= 64 && k < 128) v = *(const f32x4*)(wt3 + (k - 64)); }
        else if (n >= 16 && n < 144){ if (k >= 128)           v = *(const f32x4*)(wz3 + (size_t)(n - 16) * 64 + (k - 128)); }
        ushort4v h, l;
        #pragma unroll
        for (int j = 0; j < 4; ++j) { unsigned short hh, ll; split_bf16(v[j], hh, ll); h[j] = hh; l[j] = ll; }
        *(ushort4v*)(w3h + idx) = h;
        *(ushort4v*)(w3l + idx) = l;
    } else {
        for (int i = t; i < 720; i += 256) {
            if (i < 384)      b1c[i] = (i < 128) ? b1[i] : (i < 256) ? bt1[i - 128] : bz1[i - 256];
            else if (i < 576) { int j = i - 384; b2c[j] = (j < 64) ? b2[j] : (j < 128) ? bt2[j - 64] : bz2[j - 128]; }
            else              { int j = i - 576; b3c[j] = (j == 0) ? b3[0] : (j == 1) ? bt3[0] : (j < 16) ? 0.f : bz3[j - 16]; }
        }
    }
}

// ---------------- GEMM1: h1 = relu(s @ W1cat^T + b1c) ----------------
// 512 blocks x 512 thr; 16 rows/block; wave w handles n-tiles w*3..w*3+2
__global__ __launch_bounds__(512, 2) void k_gemm1(
    const float* __restrict__ s, const unsigned short* __restrict__ wh,
    const unsigned short* __restrict__ wl, const float* __restrict__ bias,
    unsigned short* __restrict__ h1h, unsigned short* __restrict__ h1l)
{
    const int t = threadIdx.x;
    const int lane = t & 63;
    const int w = t >> 6;
    const int l15 = lane & 15, lg = lane >> 4;
    const int m = blockIdx.x * 16 + l15;
    const int nbase = w * 3;

    f32x4 acc[3];
    #pragma unroll
    for (int i = 0; i < 3; ++i) acc[i] = (f32x4){0.f, 0.f, 0.f, 0.f};

    const float* srow = s + (size_t)m * SD;
    for (int kt = 0; kt < 16; ++kt) {
        const int k0 = kt * 32 + lg * 8;
        f32x4 xa = *(const f32x4*)(srow + k0);
        f32x4 xb = *(const f32x4*)(srow + k0 + 4);
        U8 xh, xl;
        #pragma unroll
        for (int j = 0; j < 4; ++j) {
            split_bf16(xa[j], xh.u[j], xl.u[j]);
            split_bf16(xb[j], xh.u[4 + j], xl.u[4 + j]);
        }
        #pragma unroll
        for (int i = 0; i < 3; ++i) {
            const size_t off = (size_t)((nbase + i) * 16 + l15) * 512 + k0;
            bf16x8 bh = *(const bf16x8*)(wh + off);
            bf16x8 bl = *(const bf16x8*)(wl + off);
            acc[i] = __builtin_amdgcn_mfma_f32_16x16x32_bf16(bh, xh.b, acc[i], 0, 0, 0);
            acc[i] = __builtin_amdgcn_mfma_f32_16x16x32_bf16(bl, xh.b, acc[i], 0, 0, 0);
            acc[i] = __builtin_amdgcn_mfma_f32_16x16x32_bf16(bh, xl.b, acc[i], 0, 0, 0);
        }
    }
    #pragma unroll
    for (int i = 0; i < 3; ++i) {
        const int n0 = (nbase + i) * 16 + lg * 4;
        f32x4 bv = *(const f32x4*)(bias + n0);
        f32x4 v = acc[i] + bv;
        ushort4v vh, vl;
        #pragma unroll
        for (int r = 0; r < 4; ++r) {
            float x = fmaxf(v[r], 0.f);
            unsigned short hh, ll; split_bf16(x, hh, ll);
            vh[r] = hh; vl[r] = ll;
        }
        *(ushort4v*)(h1h + (size_t)m * 384 + n0) = vh;
        *(ushort4v*)(h1l + (size_t)m * 384 + n0) = vl;
    }
}

// ---------------- GEMM2: h2 = relu(h1 @ W2cat^T + b2c) ----------------
// 512 blocks x 384 thr; 16 rows/block; wave w handles n-tiles w*2..w*2+1
__global__ __launch_bounds__(384, 2) void k_gemm2(
    const unsigned short* __restrict__ xh_, const unsigned short* __restrict__ xl_,
    const unsigned short* __restrict__ wh, const unsigned short* __restrict__ wl,
    const float* __restrict__ bias,
    unsigned short* __restrict__ h2h, unsigned short* __restrict__ h2l)
{
    const int t = threadIdx.x;
    const int lane = t & 63;
    const int w = t >> 6;
    const int l15 = lane & 15, lg = lane >> 4;
    const int m = blockIdx.x * 16 + l15;
    const int nbase = w * 2;

    f32x4 acc[2];
    #pragma unroll
    for (int i = 0; i < 2; ++i) acc[i] = (f32x4){0.f, 0.f, 0.f, 0.f};

    const unsigned short* xh = xh_ + (size_t)m * 384;
    const unsigned short* xl = xl_ + (size_t)m * 384;
    for (int kt = 0; kt < 12; ++kt) {
        const int k0 = kt * 32 + lg * 8;
        bf16x8 axh = *(const bf16x8*)(xh + k0);
        bf16x8 axl = *(const bf16x8*)(xl + k0);
        #pragma unroll
        for (int i = 0; i < 2; ++i) {
            const size_t off = (size_t)((nbase + i) * 16 + l15) * 384 + k0;
            bf16x8 bh = *(const bf16x8*)(wh + off);
            bf16x8 bl = *(const bf16x8*)(wl + off);
            acc[i] = __builtin_amdgcn_mfma_f32_16x16x32_bf16(bh, axh, acc[i], 0, 0, 0);
            acc[i] = __builtin_amdgcn_mfma_f32_16x16x32_bf16(bl, axh, acc[i], 0, 0, 0);
            acc[i] = __builtin_amdgcn_mfma_f32_16x16x32_bf16(bh, axl, acc[i], 0, 0, 0);
        }
    }
    #pragma unroll
    for (int i = 0; i < 2; ++i) {
        const int n0 = (nbase + i) * 16 + lg * 4;
        f32x4 bv = *(const f32x4*)(bias + n0);
        f32x4 v = acc[i] + bv;
        ushort4v vh, vl;
        #pragma unroll
        for (int r = 0; r < 4; ++r) {
            float x = fmaxf(v[r], 0.f);
            unsigned short hh, ll; split_bf16(x, hh, ll);
            vh[r] = hh; vl[r] = ll;
        }
        *(ushort4v*)(h2h + (size_t)m * 192 + n0) = vh;
        *(ushort4v*)(h2l + (size_t)m * 192 + n0) = vl;
    }
}

// ---------------- GEMM3: 512 blocks x 512 thr; 16 rows/block; wave w -> tile w (+tile 8 for w==7) ----------------
__global__ __launch_bounds__(512, 2) void k_gemm3(
    const unsigned short* __restrict__ xh_, const unsigned short* __restrict__ xl_,
    const unsigned short* __restrict__ wh, const unsigned short* __restrict__ wl,
    const float* __restrict__ bias,
    unsigned short* __restrict__ zb, float* __restrict__ sq, float* __restrict__ alpha)
{
    __shared__ float sred[8][16];
    const int t = threadIdx.x;
    const int lane = t & 63;
    const int w = t >> 6;
    const int l15 = lane & 15, lg = lane >> 4;
    const int m = blockIdx.x * 16 + l15;
    const int nb = w;
    const int nc = (w == 7) ? 2 : 1;

    f32x4 acc[2];
    #pragma unroll
    for (int i = 0; i < 2; ++i) acc[i] = (f32x4){0.f, 0.f, 0.f, 0.f};

    const unsigned short* xh = xh_ + (size_t)m * 192;
    const unsigned short* xl = xl_ + (size_t)m * 192;
    for (int kt = 0; kt < 6; ++kt) {
        const int k0 = kt * 32 + lg * 8;
        bf16x8 axh = *(const bf16x8*)(xh + k0);
        bf16x8 axl = *(const bf16x8*)(xl + k0);
        #pragma unroll
        for (int i = 0; i < 2; ++i) {
            if (i < nc) {
                const size_t off = (size_t)((nb + i) * 16 + l15) * 192 + k0;
                bf16x8 bh = *(const bf16x8*)(wh + off);
                bf16x8 bl = *(const bf16x8*)(wl + off);
                acc[i] = __builtin_amdgcn_mfma_f32_16x16x32_bf16(bh, axh, acc[i], 0, 0, 0);
                acc[i] = __builtin_amdgcn_mfma_f32_16x16x32_bf16(bl, axh, acc[i], 0, 0, 0);
                acc[i] = __builtin_amdgcn_mfma_f32_16x16x32_bf16(bh, axl, acc[i], 0, 0, 0);
            }
        }
    }

    float ssq = 0.f;
    float pred = 0.f, tgt = 0.f;
    #pragma unroll
    for (int i = 0; i < 2; ++i) {
        if (i < nc) {
            const int ntg = nb + i;
            const int n0 = ntg * 16 + lg * 4;
            f32x4 bv = *(const f32x4*)(bias + n0);
            f32x4 v = acc[i] + bv;
            if (ntg == 0) {
                if (lg == 0) { pred = v.x; tgt = v.y; }
            } else {
                ushort4v zu;
                #pragma unroll
                for (int r = 0; r < 4; ++r) {
                    unsigned short us = f32_to_bf16_rne(v[r]);
                    float zf = __uint_as_float(((unsigned int)us) << 16);
                    ssq += zf * zf;
                    zu[r] = us;
                }
                *(ushort4v*)(zb + (size_t)m * FDIM + (ntg - 1) * 16 + lg * 4) = zu;
            }
        }
    }
    ssq += __shfl_xor(ssq, 16);
    ssq += __shfl_xor(ssq, 32);
    if (lg == 0) sred[w][l15] = ssq;
    __syncthreads();
    if (t < 16) {
        float sm = 0.f;
        #pragma unroll
        for (int ww = 0; ww < 8; ++ww) sm += sred[ww][t];
        sq[blockIdx.x * 16 + t] = sm;
    }
    if (w == 0 && lg == 0) {
        float d = pred - tgt;
        alpha[m] = d * d;
    }
}

// ---------------- K2: pairwise + threshold-filtered top-10 ----------------
// 1024 blocks x 256 thr; block: split = b&15 (shared by all 4 waves -> L1 reuse),
// qg = (b>>4)*4 + wave. Wave: 32 queries x 512 candidates (32 tiles).
__global__ __launch_bounds__(256, 4) void k_pairs(
    const unsigned short* __restrict__ zb, const float* __restrict__ sq,
    float* __restrict__ part)
{
    __shared__ float buf[4][2][64][BCAP];
    __shared__ float sqs[512];
    const int lane = threadIdx.x & 63;
    const int wv = threadIdx.x >> 6;
    const int split = blockIdx.x & 15;
    const int qg = (blockIdx.x >> 4) * 4 + wv;
    const int l15 = lane & 15, lg = lane >> 4;
    const int c0 = split * 512;

    // stage this split's sq slab into LDS
    sqs[threadIdx.x] = sq[c0 + threadIdx.x];
    sqs[threadIdx.x + 256] = sq[c0 + threadIdx.x + 256];
    __syncthreads();

    float* bp0 = &buf[wv][0][lane][0];
    float* bp1 = &buf[wv][1][lane][0];

    const int qid0 = qg * 32 + l15;
    const int qid1 = qg * 32 + 16 + l15;
    bf16x8 bq[2][4];
    #pragma unroll
    for (int kk = 0; kk < 4; ++kk) {
        bq[0][kk] = *(const bf16x8*)(zb + (size_t)qid0 * FDIM + kk * 32 + lg * 8);
        bq[1][kk] = *(const bf16x8*)(zb + (size_t)qid1 * FDIM + kk * 32 + lg * 8);
    }

    float vals[2][10];
    #pragma unroll
    for (int qt = 0; qt < 2; ++qt)
        #pragma unroll
        for (int i = 0; i < 10; ++i) vals[qt][i] = BIGF;
    float thr0 = BIGF, thr1 = BIGF;
    int cnt0 = 0, cnt1 = 0;

    // prefetch tile 0
    bf16x8 av[4];
    {
        const unsigned short* zp = zb + (size_t)(c0 + l15) * FDIM + lg * 8;
        #pragma unroll
        for (int kk = 0; kk < 4; ++kk) av[kk] = *(const bf16x8*)(zp + kk * 32);
    }

    for (int tile = 0; tile < 32; ++tile) {
        f32x4 acc0 = {0.f, 0.f, 0.f, 0.f};
        f32x4 acc1 = {0.f, 0.f, 0.f, 0.f};
        #pragma unroll
        for (int kk = 0; kk < 4; ++kk) {
            acc0 = __builtin_amdgcn_mfma_f32_16x16x32_bf16(av[kk], bq[0][kk], acc0, 0, 0, 0);
            acc1 = __builtin_amdgcn_mfma_f32_16x16x32_bf16(av[kk], bq[1][kk], acc1, 0, 0, 0);
        }
        // prefetch next tile while epilogue runs
        if (tile < 31) {
            const unsigned short* zp = zb + (size_t)(c0 + (tile + 1) * 16 + l15) * FDIM + lg * 8;
            #pragma unroll
            for (int kk = 0; kk < 4; ++kk) av[kk] = *(const bf16x8*)(zp + kk * 32);
        }
        f32x4 sqv = *(const f32x4*)(&sqs[tile * 16 + lg * 4]);
        #pragma unroll
        for (int r = 0; r < 4; ++r) {
            const int j = c0 + tile * 16 + lg * 4 + r;
            float v0 = fmaf(-2.0f, acc0[r], sqv[r]);     // key = dist^2 - sq_i
            int ok0 = (int)(v0 < thr0) & (int)(j != qid0);
            bp0[cnt0] = v0;
            cnt0 += ok0;
            float v1 = fmaf(-2.0f, acc1[r], sqv[r]);
            int ok1 = (int)(v1 < thr1) & (int)(j != qid1);
            bp1[cnt1] = v1;
            cnt1 += ok1;
        }
        if (__any(cnt0 >= TRIG)) { compact16(vals[0], bp0, cnt0); thr0 = vals[0][9]; cnt0 = 0; }
        if (__any(cnt1 >= TRIG)) { compact16(vals[1], bp1, cnt1); thr1 = vals[1][9]; cnt1 = 0; }
    }
    compact16(vals[0], bp0, cnt0);
    compact16(vals[1], bp1, cnt1);

    // merge lane-groups: ^16 (min-trick) -> bitonic resort -> ^32 (min-trick)
    #pragma unroll
    for (int qt = 0; qt < 2; ++qt) {
        float wk[10];
        #pragma unroll
        for (int i = 0; i < 10; ++i) {
            float o = __shfl_xor(vals[qt][9 - i], 16);
            wk[i] = fminf(vals[qt][i], o);
        }
        sortBitonic10(wk);
        float m1[10];
        #pragma unroll
        for (int i = 0; i < 10; ++i) {
            float o = __shfl_xor(wk[9 - i], 32);
            m1[i] = fminf(wk[i], o);
        }
        if (lg == 0) {
            const int qid = (qt == 0) ? qid0 : qid1;
            float* dst = part + ((size_t)split * NROWS + qid) * KNN;
            #pragma unroll
            for (int i = 0; i < 10; ++i) dst[i] = m1[i];
        }
    }
}

// ---------------- K3: merge 16 partial (unsorted) lists ----------------
__global__ __launch_bounds__(256) void k_merge(
    const float* __restrict__ part, const float* __restrict__ sq,
    float* __restrict__ sumk, float* __restrict__ total)
{
    const int q = blockIdx.x * 256 + threadIdx.x;
    float vals[10];
    #pragma unroll
    for (int i = 0; i < 10; ++i) vals[i] = BIGF;
    for (int seg = 0; seg < NSEG; ++seg) {
        const float* p = part + ((size_t)seg * NROWS + q) * KNN;
        #pragma unroll
        for (int i = 0; i < 10; ++i) {
            float tv = p[i];
            if (tv < vals[9]) insert10(vals, tv);
        }
    }
    float sqq = sq[q];
    float sum = 0.f;
    #pragma unroll
    for (int i = 0; i < 10; ++i) {
        float raw = sqq + vals[i];
        sum += (raw > 0.f) ? sqrtf(raw) : 0.f;
    }
    sumk[q] = sum;

    __shared__ float red[4];
    float bsum = sum;
    #pragma unroll
    for (int off = 32; off > 0; off >>= 1) bsum += __shfl_down(bsum, off);
    if ((threadIdx.x & 63) == 0) red[threadIdx.x >> 6] = bsum;
    __syncthreads();
    if (threadIdx.x == 0) atomicAdd(total, red[0] + red[1] + red[2] + red[3]);
}

// ---------------- K4: finalize ----------------
__global__ __launch_bounds__(256) void k_final(
    const float* __restrict__ sumk, const float* __restrict__ alpha,
    const float* __restrict__ total, float* __restrict__ out)
{
    const int q = blockIdx.x * 256 + threadIdx.x;
    float mean = (*total) * (1.0f / NROWS);
    float m2 = mean * mean;
    float sk = sumk[q];
    float x = (sk * sk) / m2;
    float knn = EPS_CONST / (x + EPS_CONST);
    float rep = 1.0f / (sqrtf(knn) + C_CONST);
    float a = alpha[q];
    a = fminf(fmaxf(a, 1.0f), L_CONST);
    out[q] = rep * a;
}

extern "C" void kernel_launch(void* const* d_in, const int* in_sizes, int n_in,
                              void* d_out, int out_size, void* d_ws, size_t ws_size,
                              hipStream_t stream) {
    const float* s   = (const float*)d_in[0];
    const float* w1  = (const float*)d_in[1];
    const float* b1  = (const float*)d_in[2];
    const float* w2  = (const float*)d_in[3];
    const float* b2  = (const float*)d_in[4];
    const float* w3  = (const float*)d_in[5];
    const float* b3  = (const float*)d_in[6];
    const float* wt1 = (const float*)d_in[7];
    const float* bt1 = (const float*)d_in[8];
    const float* wt2 = (const float*)d_in[9];
    const float* bt2 = (const float*)d_in[10];
    const float* wt3 = (const float*)d_in[11];
    const float* bt3 = (const float*)d_in[12];
    const float* wz1 = (const float*)d_in[13];
    const float* bz1 = (const float*)d_in[14];
    const float* wz2 = (const float*)d_in[15];
    const float* bz2 = (const float*)d_in[16];
    const float* wz3 = (const float*)d_in[17];
    const float* bz3 = (const float*)d_in[18];

    char* ws = (char*)d_ws;
    unsigned short* zb  = (unsigned short*)(ws);                // 2097152
    float* sq    = (float*)(ws + 2097152);                      // 32768
    float* alpha = (float*)(ws + 2129920);                      // 32768
    float* part  = (float*)(ws + 2162688);                      // 16*8192*10*4 = 5242880
    float* sumk  = (float*)(ws + 7405568);                      // 32768
    float* total = (float*)(ws + 7438336);                      // 256
    unsigned short* h1h = (unsigned short*)(ws + 7438592);      // 6291456
    unsigned short* h1l = (unsigned short*)(ws + 13730048);     // 6291456
    unsigned short* h2h = (unsigned short*)(ws + 20021504);     // 3145728
    unsigned short* h2l = (unsigned short*)(ws + 23167232);     // 3145728
    unsigned short* w1h = (unsigned short*)(ws + 26312960);     // 393216
    unsigned short* w1l = (unsigned short*)(ws + 26706176);     // 393216
    unsigned short* w2h = (unsigned short*)(ws + 27099392);     // 147456
    unsigned short* w2l = (unsigned short*)(ws + 27246848);     // 147456
    unsigned short* w3h = (unsigned short*)(ws + 27394304);     // 55296
    unsigned short* w3l = (unsigned short*)(ws + 27449600);     // 55296
    float* b1c = (float*)(ws + 27504896);
    float* b2c = (float*)(ws + 27506432);
    float* b3c = (float*)(ws + 27507200);

    hipMemsetAsync(total, 0, sizeof(float), stream);

    k_prep<<<292, 256, 0, stream>>>(w1, wt1, wz1, w2, wt2, wz2, w3, wt3, wz3,
                                    b1, bt1, bz1, b2, bt2, bz2, b3, bt3, bz3,
                                    w1h, w1l, w2h, w2l, w3h, w3l, b1c, b2c, b3c);
    k_gemm1<<<512, 512, 0, stream>>>(s, w1h, w1l, b1c, h1h, h1l);
    k_gemm2<<<512, 384, 0, stream>>>(h1h, h1l, w2h, w2l, b2c, h2h, h2l);
    k_gemm3<<<512, 512, 0, stream>>>(h2h, h2l, w3h, w3l, b3c, zb, sq, alpha);
    k_pairs<<<1024, 256, 0, stream>>>(zb, sq, part);
    k_merge<<<32, 256, 0, stream>>>(part, sq, sumk, total);
    k_final<<<32, 256, 0, stream>>>(sumk, alpha, total, (float*)d_out);
}